// Round 1
// baseline (458.846 us; speedup 1.0000x reference)
//
#include <hip/hip_runtime.h>

typedef unsigned short u16;
typedef unsigned int u32;
typedef __bf16 bf16x8 __attribute__((ext_vector_type(8)));
typedef u16 u16x8 __attribute__((ext_vector_type(8)));
typedef u16 u16x4 __attribute__((ext_vector_type(4)));
typedef float f32x4 __attribute__((ext_vector_type(4)));

#define BHTD 8388608  // 4*16*2048*64 elements per Q/K/V tensor

__device__ __forceinline__ u16 f2bf(float f) {
  union { float f; u32 u; } x; x.f = f;
  u32 r = (x.u + 0x7FFFu + ((x.u >> 16) & 1u)) >> 16;
  return (u16)r;
}

__device__ __forceinline__ void async_copy16(const u16* gsrc, u16* ldst) {
  __builtin_amdgcn_global_load_lds(
      (const __attribute__((address_space(1))) void*)gsrc,
      (__attribute__((address_space(3))) void*)ldst, 16, 0, 0);
}

// ---------------- fp32 -> bf16 elementwise convert ----------------
__global__ __launch_bounds__(256) void conv_x_kernel(const float4* __restrict__ in,
                                                     u16x4* __restrict__ out, int n4) {
  int i = blockIdx.x * 256 + threadIdx.x;
  int stride = gridDim.x * 256;
  for (; i < n4; i += stride) {
    float4 v = in[i];
    u16x4 o = { f2bf(v.x), f2bf(v.y), f2bf(v.z), f2bf(v.w) };
    out[i] = o;
  }
}

// ---------------- fp32 [K][N] -> bf16 transposed [N][K] ----------------
__global__ __launch_bounds__(256) void transpose_bf16(const float* __restrict__ W,
                                                      u16* __restrict__ Wt, int K, int N) {
  __shared__ float t[64][65];
  int c0 = blockIdx.x * 64;  // col block (N)
  int r0 = blockIdx.y * 64;  // row block (K)
  int c = threadIdx.x & 63;
  int r4 = threadIdx.x >> 6;
#pragma unroll
  for (int j = 0; j < 16; ++j) {
    int r = j * 4 + r4;
    t[r][c] = W[(size_t)(r0 + r) * N + (c0 + c)];
  }
  __syncthreads();
#pragma unroll
  for (int j = 0; j < 16; ++j) {
    int n = j * 4 + r4;
    Wt[(size_t)(c0 + n) * K + (r0 + c)] = f2bf(t[c][n]);
  }
}

// ---------------- bf16 GEMM: C[M][N] = A[M][1024] * Bt[N][1024]^T + bias ----------------
// 128x128 tile, 4 waves (2x2), BK=64, global_load_lds staging with XOR slot swizzle.
// MODE 0: scatter to QKV [3][B=4][H=16][T=2048][D=64] bf16.  MODE 1: fp32 out [M][1024].
template <int MODE>
__global__ __launch_bounds__(256) void gemm_bf16(const u16* __restrict__ A,
                                                 const u16* __restrict__ Bt,
                                                 const float* __restrict__ bias,
                                                 float* __restrict__ outp,
                                                 u16* __restrict__ qkv, int grid_n) {
  __shared__ __attribute__((aligned(16))) u16 A_lds[128 * 64];
  __shared__ __attribute__((aligned(16))) u16 B_lds[128 * 64];
  const int tid = threadIdx.x;
  const int lane = tid & 63, wave = tid >> 6;
  const int wr = wave >> 1, wc = wave & 1;
  const int bn = blockIdx.x % grid_n, bm = blockIdx.x / grid_n;
  const int m0 = bm * 128, n0 = bn * 128;
  const int g = lane >> 4, c16 = lane & 15;
  const int lrow = lane >> 3, lslot = lane & 7;

  f32x4 acc[4][4] = {};

  for (int kt = 0; kt < 16; ++kt) {
#pragma unroll
    for (int i = 0; i < 4; ++i) {
      int mloc = (wave * 4 + i) * 8 + lrow;
      int col = kt * 64 + ((lslot ^ (mloc & 7)) << 3);  // pre-swizzled global source
      async_copy16(&A[(size_t)(m0 + mloc) * 1024 + col], &A_lds[(wave * 4 + i) * 512]);
      async_copy16(&Bt[(size_t)(n0 + mloc) * 1024 + col], &B_lds[(wave * 4 + i) * 512]);
    }
    __syncthreads();  // compiler drains vmcnt before barrier
#pragma unroll
    for (int kk = 0; kk < 2; ++kk) {
      bf16x8 af[4], bfr[4];
#pragma unroll
      for (int mb = 0; mb < 4; ++mb) {
        int row = wr * 64 + mb * 16 + c16;
        int slot = (kk * 4 + g) ^ (row & 7);
        af[mb] = *(const bf16x8*)&A_lds[row * 64 + slot * 8];
        int rowb = wc * 64 + mb * 16 + c16;
        int slotb = (kk * 4 + g) ^ (rowb & 7);
        bfr[mb] = *(const bf16x8*)&B_lds[rowb * 64 + slotb * 8];
      }
#pragma unroll
      for (int mb = 0; mb < 4; ++mb)
#pragma unroll
        for (int nb = 0; nb < 4; ++nb)
          acc[mb][nb] = __builtin_amdgcn_mfma_f32_16x16x32_bf16(af[mb], bfr[nb], acc[mb][nb], 0, 0, 0);
    }
    __syncthreads();
  }

  float bv[4];
#pragma unroll
  for (int nb = 0; nb < 4; ++nb) bv[nb] = bias[n0 + wc * 64 + nb * 16 + c16];

#pragma unroll
  for (int mb = 0; mb < 4; ++mb) {
    int row0 = m0 + wr * 64 + mb * 16 + g * 4;
#pragma unroll
    for (int nb = 0; nb < 4; ++nb) {
      int col = n0 + wc * 64 + nb * 16 + c16;
#pragma unroll
      for (int r = 0; r < 4; ++r) {
        float v = acc[mb][nb][r] + bv[nb];
        int row = row0 + r;
        if (MODE == 0) {
          int sel = col >> 10, ci = col & 1023;
          int bb = row >> 11, t = row & 2047;
          qkv[(size_t)sel * BHTD + (((size_t)(bb * 16 + (ci >> 6)) * 2048 + t) << 6) + (ci & 63)] =
              f2bf(v);
        } else {
          outp[((size_t)row << 10) + col] = v;
        }
      }
    }
  }
}

// ---------------- causal flash attention: 1 block = (b, h, 64-row q tile) ----------------
__global__ __launch_bounds__(256) void attn_fwd(const u16* __restrict__ Q,
                                                const u16* __restrict__ K,
                                                const u16* __restrict__ V,
                                                u16* __restrict__ Y) {
  __shared__ __attribute__((aligned(16))) u16 Vt[64 * 64];      // [d][kv], kv-slot swizzled
  __shared__ __attribute__((aligned(16))) u16 P[4][16 * 64];    // per-wave [q][kv], swizzled
  const float NEG_INF = -__builtin_inff();

  int bid = blockIdx.x;
  int qt = bid & 31, h = (bid >> 5) & 15, b = bid >> 9;
  size_t hb = (size_t)(b * 16 + h) * 2048 * 64;
  const u16* Qh = Q + hb;
  const u16* Kh = K + hb;
  const u16* Vh = V + hb;
  int tid = threadIdx.x, lane = tid & 63, w = tid >> 6;
  int g = lane >> 4, c16 = lane & 15;
  int q0 = qt * 64;
  int c8 = tid & 7;

  bf16x8 qf[2];
  {
    int qrow = q0 + w * 16 + c16;
    qf[0] = *(const bf16x8*)&Qh[(size_t)qrow * 64 + 8 * g];
    qf[1] = *(const bf16x8*)&Qh[(size_t)qrow * 64 + 32 + 8 * g];
  }

  float m[4], lsum[4];
  f32x4 o[4] = {};
#pragma unroll
  for (int r = 0; r < 4; ++r) { m[r] = NEG_INF; lsum[r] = 0.f; }

  for (int kv0 = 0; kv0 <= q0; kv0 += 64) {
    __syncthreads();  // previous tile's Vt reads done
#pragma unroll
    for (int it = 0; it < 2; ++it) {
      int kvr = it * 32 + (tid >> 3);
      u16x8 vv = *(const u16x8*)&Vh[(size_t)(kv0 + kvr) * 64 + c8 * 8];
#pragma unroll
      for (int e0 = 0; e0 < 8; ++e0) {
        int e = (e0 + c8) & 7;          // rotate write order: bank-conflict-free
        int d = c8 * 8 + e;             // d&7 == e
        Vt[d * 64 + ((((kvr >> 3) ^ e)) << 3) + (kvr & 7)] = vv[e];
      }
    }
    __syncthreads();

    // S = Q K^T  (K fragments direct from global, L2-resident)
    f32x4 s[4] = {};
#pragma unroll
    for (int kk = 0; kk < 2; ++kk)
#pragma unroll
      for (int nb = 0; nb < 4; ++nb) {
        bf16x8 kf = *(const bf16x8*)&Kh[(size_t)(kv0 + nb * 16 + c16) * 64 + kk * 32 + 8 * g];
        s[nb] = __builtin_amdgcn_mfma_f32_16x16x32_bf16(qf[kk], kf, s[nb], 0, 0, 0);
      }

    // mask + online softmax (rows live across 16-lane groups)
#pragma unroll
    for (int r = 0; r < 4; ++r) {
      int qg = q0 + w * 16 + g * 4 + r;
      float rm = NEG_INF;
#pragma unroll
      for (int nb = 0; nb < 4; ++nb) {
        float sv = s[nb][r] * 0.125f;
        int kvg = kv0 + nb * 16 + c16;
        if (kvg > qg) sv = NEG_INF;
        s[nb][r] = sv;
        rm = fmaxf(rm, sv);
      }
#pragma unroll
      for (int off = 1; off < 16; off <<= 1) rm = fmaxf(rm, __shfl_xor(rm, off));
      float mn = fmaxf(m[r], rm);       // finite from first tile onward
      float alpha = __expf(m[r] - mn);
      float rs = 0.f;
#pragma unroll
      for (int nb = 0; nb < 4; ++nb) {
        float p = __expf(s[nb][r] - mn);
        s[nb][r] = p;
        rs += p;
      }
#pragma unroll
      for (int off = 1; off < 16; off <<= 1) rs += __shfl_xor(rs, off);
      m[r] = mn;
      lsum[r] = lsum[r] * alpha + rs;
#pragma unroll
      for (int nb = 0; nb < 4; ++nb) o[nb][r] *= alpha;
    }

    // P -> per-wave LDS (swizzled), then PV
    u16* Pw = &P[w][0];
#pragma unroll
    for (int nb = 0; nb < 4; ++nb)
#pragma unroll
      for (int r = 0; r < 4; ++r) {
        int row = g * 4 + r;
        int col = nb * 16 + c16;
        Pw[row * 64 + (((col >> 3) ^ (row & 7)) << 3) + (col & 7)] = f2bf(s[nb][r]);
      }

#pragma unroll
    for (int kk = 0; kk < 2; ++kk) {
      bf16x8 pf = *(const bf16x8*)&Pw[c16 * 64 + (((kk * 4 + g) ^ (c16 & 7)) << 3)];
#pragma unroll
      for (int nb = 0; nb < 4; ++nb) {
        int vrow = c16 + 16 * nb;
        bf16x8 vf = *(const bf16x8*)&Vt[vrow * 64 + (((kk * 4 + g) ^ (vrow & 7)) << 3)];
        o[nb] = __builtin_amdgcn_mfma_f32_16x16x32_bf16(pf, vf, o[nb], 0, 0, 0);
      }
    }
  }

  // epilogue: y[b][t][h*64+d] bf16
  size_t yb = ((size_t)b * 2048) * 1024 + (size_t)h * 64;
#pragma unroll
  for (int nb = 0; nb < 4; ++nb)
#pragma unroll
    for (int r = 0; r < 4; ++r) {
      int row = q0 + w * 16 + g * 4 + r;
      int col = nb * 16 + c16;
      Y[yb + (size_t)row * 1024 + col] = f2bf(o[nb][r] / lsum[r]);
    }
}

extern "C" void kernel_launch(void* const* d_in, const int* in_sizes, int n_in,
                              void* d_out, int out_size, void* d_ws, size_t ws_size,
                              hipStream_t stream) {
  (void)in_sizes; (void)n_in; (void)out_size; (void)ws_size;
  const float* x      = (const float*)d_in[0];
  const float* W_attn = (const float*)d_in[1];
  const float* b_attn = (const float*)d_in[2];
  const float* W_proj = (const float*)d_in[3];
  const float* b_proj = (const float*)d_in[4];
  float* out = (float*)d_out;

  char* ws = (char*)d_ws;
  u16* Xb  = (u16*)(ws);                                   // 8192*1024 bf16 (reused as Yb)
  u16* Wt  = (u16*)(ws + 16777216);                        // 3072*1024 bf16
  u16* Wpt = (u16*)(ws + 16777216 + 6291456);              // 1024*1024 bf16
  u16* QKV = (u16*)(ws + 16777216 + 6291456 + 2097152);    // 3 * 8388608 bf16
  u16* Yb  = Xb;

  conv_x_kernel<<<2048, 256, 0, stream>>>((const float4*)x, (u16x4*)Xb, 2097152);
  transpose_bf16<<<dim3(48, 16), 256, 0, stream>>>(W_attn, Wt, 1024, 3072);
  transpose_bf16<<<dim3(16, 16), 256, 0, stream>>>(W_proj, Wpt, 1024, 1024);
  gemm_bf16<0><<<1536, 256, 0, stream>>>(Xb, Wt, b_attn, nullptr, QKV, 24);
  attn_fwd<<<2048, 256, 0, stream>>>(QKV, QKV + BHTD, QKV + 2 * BHTD, Yb);
  gemm_bf16<1><<<512, 256, 0, stream>>>(Yb, Wpt, b_proj, out, nullptr, 8);
}

// Round 2
// 375.134 us; speedup vs baseline: 1.2232x; 1.2232x over previous
//
#include <hip/hip_runtime.h>

typedef unsigned short u16;
typedef unsigned int u32;
typedef __bf16 bf16x8 __attribute__((ext_vector_type(8)));
typedef u16 u16x8 __attribute__((ext_vector_type(8)));
typedef u16 u16x4 __attribute__((ext_vector_type(4)));
typedef float f32x4 __attribute__((ext_vector_type(4)));

#define BHTD 8388608  // 4*16*2048*64 elements per Q/K/V tensor

__device__ __forceinline__ u16 f2bf(float f) {
  union { float f; u32 u; } x; x.f = f;
  u32 r = (x.u + 0x7FFFu + ((x.u >> 16) & 1u)) >> 16;
  return (u16)r;
}

__device__ __forceinline__ void async_copy16(const u16* gsrc, u16* ldst) {
  __builtin_amdgcn_global_load_lds(
      (const __attribute__((address_space(1))) void*)gsrc,
      (__attribute__((address_space(3))) void*)ldst, 16, 0, 0);
}

// ---------------- fp32 -> bf16 elementwise convert ----------------
__global__ __launch_bounds__(256) void conv_x_kernel(const float4* __restrict__ in,
                                                     u16x4* __restrict__ out, int n4) {
  int i = blockIdx.x * 256 + threadIdx.x;
  int stride = gridDim.x * 256;
  for (; i < n4; i += stride) {
    float4 v = in[i];
    u16x4 o = { f2bf(v.x), f2bf(v.y), f2bf(v.z), f2bf(v.w) };
    out[i] = o;
  }
}

// ---------------- fp32 [K][N] -> bf16 transposed [N][K] ----------------
__global__ __launch_bounds__(256) void transpose_bf16(const float* __restrict__ W,
                                                      u16* __restrict__ Wt, int K, int N) {
  __shared__ float t[64][65];
  int c0 = blockIdx.x * 64;  // col block (N)
  int r0 = blockIdx.y * 64;  // row block (K)
  int c = threadIdx.x & 63;
  int r4 = threadIdx.x >> 6;
#pragma unroll
  for (int j = 0; j < 16; ++j) {
    int r = j * 4 + r4;
    t[r][c] = W[(size_t)(r0 + r) * N + (c0 + c)];
  }
  __syncthreads();
#pragma unroll
  for (int j = 0; j < 16; ++j) {
    int n = j * 4 + r4;
    Wt[(size_t)(c0 + n) * K + (r0 + c)] = f2bf(t[c][n]);
  }
}

// ---------------- bf16 GEMM: C[M][N] = A[M][1024] * Bt[N][1024]^T + bias ----------------
// 128x128 tile, 4 waves (2x2), BK=64, global_load_lds staging with XOR slot swizzle.
// MODE 0: scatter to QKV; Q,K as [B][H][T][64], V TRANSPOSED as [B][H][64][T] (bf16).
// MODE 1: fp32 out [M][1024].
template <int MODE>
__global__ __launch_bounds__(256) void gemm_bf16(const u16* __restrict__ A,
                                                 const u16* __restrict__ Bt,
                                                 const float* __restrict__ bias,
                                                 float* __restrict__ outp,
                                                 u16* __restrict__ qkv, int grid_n) {
  __shared__ __attribute__((aligned(16))) u16 A_lds[128 * 64];
  __shared__ __attribute__((aligned(16))) u16 B_lds[128 * 64];
  const int tid = threadIdx.x;
  const int lane = tid & 63, wave = tid >> 6;
  const int wr = wave >> 1, wc = wave & 1;
  const int bn = blockIdx.x % grid_n, bm = blockIdx.x / grid_n;
  const int m0 = bm * 128, n0 = bn * 128;
  const int g = lane >> 4, c16 = lane & 15;
  const int lrow = lane >> 3, lslot = lane & 7;

  f32x4 acc[4][4] = {};

  for (int kt = 0; kt < 16; ++kt) {
#pragma unroll
    for (int i = 0; i < 4; ++i) {
      int mloc = (wave * 4 + i) * 8 + lrow;
      int col = kt * 64 + ((lslot ^ (mloc & 7)) << 3);  // pre-swizzled global source
      async_copy16(&A[(size_t)(m0 + mloc) * 1024 + col], &A_lds[(wave * 4 + i) * 512]);
      async_copy16(&Bt[(size_t)(n0 + mloc) * 1024 + col], &B_lds[(wave * 4 + i) * 512]);
    }
    __syncthreads();  // compiler drains vmcnt before barrier
#pragma unroll
    for (int kk = 0; kk < 2; ++kk) {
      bf16x8 af[4], bfr[4];
#pragma unroll
      for (int mb = 0; mb < 4; ++mb) {
        int row = wr * 64 + mb * 16 + c16;
        int slot = (kk * 4 + g) ^ (row & 7);
        af[mb] = *(const bf16x8*)&A_lds[row * 64 + slot * 8];
        int rowb = wc * 64 + mb * 16 + c16;
        int slotb = (kk * 4 + g) ^ (rowb & 7);
        bfr[mb] = *(const bf16x8*)&B_lds[rowb * 64 + slotb * 8];
      }
#pragma unroll
      for (int mb = 0; mb < 4; ++mb)
#pragma unroll
        for (int nb = 0; nb < 4; ++nb)
          acc[mb][nb] = __builtin_amdgcn_mfma_f32_16x16x32_bf16(af[mb], bfr[nb], acc[mb][nb], 0, 0, 0);
    }
    __syncthreads();
  }

  float bv[4];
#pragma unroll
  for (int nb = 0; nb < 4; ++nb) bv[nb] = bias[n0 + wc * 64 + nb * 16 + c16];

#pragma unroll
  for (int mb = 0; mb < 4; ++mb) {
    int row0 = m0 + wr * 64 + mb * 16 + g * 4;
#pragma unroll
    for (int nb = 0; nb < 4; ++nb) {
      int col = n0 + wc * 64 + nb * 16 + c16;
      float bvn = bv[nb];
      if (MODE == 0) {
        int sel = col >> 10, ci = col & 1023;
        int hh = ci >> 6, d = ci & 63;
        int bb = row0 >> 11, t0 = row0 & 2047;
        if (sel == 2) {
          // V transposed: [bh][d][t], 4 consecutive t -> one 8B store
          u16x4 pk;
#pragma unroll
          for (int r = 0; r < 4; ++r) pk[r] = f2bf(acc[mb][nb][r] + bvn);
          *(u16x4*)&qkv[(size_t)2 * BHTD + (((size_t)(bb * 16 + hh) * 64 + d) << 11) + t0] = pk;
        } else {
#pragma unroll
          for (int r = 0; r < 4; ++r) {
            qkv[(size_t)sel * BHTD + (((size_t)(bb * 16 + hh) * 2048 + t0 + r) << 6) + d] =
                f2bf(acc[mb][nb][r] + bvn);
          }
        }
      } else {
#pragma unroll
        for (int r = 0; r < 4; ++r)
          outp[((size_t)(row0 + r) << 10) + col] = acc[mb][nb][r] + bvn;
      }
    }
  }
}

// ---------------- causal flash attention ----------------
// 1 block = (qt, b, h); bid = qt*64 + (b*16+h) so concurrent blocks mix qt values
// (load balance) and each XCD sees only 8 distinct heads (K+V working set ~4MB = L2).
// V is pre-transposed [bh][d][t] -> PV B-fragments load directly from global.
// No __syncthreads in the kv loop; P staged in wave-private LDS.
__global__ __launch_bounds__(256) void attn_fwd(const u16* __restrict__ Q,
                                                const u16* __restrict__ K,
                                                const u16* __restrict__ VT,
                                                u16* __restrict__ Y) {
  __shared__ __attribute__((aligned(16))) u16 P[4][16 * 64];  // per-wave [q][kv], swizzled
  const float NEG_INF = -__builtin_inff();

  int bid = blockIdx.x;
  int qt = bid >> 6, hd = bid & 63;
  int b = hd >> 4, h = hd & 15;
  size_t hb = (size_t)hd * 2048 * 64;
  const u16* Qh = Q + hb;
  const u16* Kh = K + hb;
  const u16* Vh = VT + hb;  // [d][t] per head
  int tid = threadIdx.x, lane = tid & 63, w = tid >> 6;
  int g = lane >> 4, c16 = lane & 15;
  int q0 = qt * 64;
  (void)b; (void)h;

  bf16x8 qf[2];
  {
    int qrow = q0 + w * 16 + c16;
    qf[0] = *(const bf16x8*)&Qh[(size_t)qrow * 64 + 8 * g];
    qf[1] = *(const bf16x8*)&Qh[(size_t)qrow * 64 + 32 + 8 * g];
  }

  float m[4], lsum[4];
  f32x4 o[4] = {};
#pragma unroll
  for (int r = 0; r < 4; ++r) { m[r] = NEG_INF; lsum[r] = 0.f; }

  u16* Pw = &P[w][0];

  for (int kv0 = 0; kv0 <= q0; kv0 += 64) {
    // S = Q K^T (raw, unscaled); K fragments direct from global (L2-resident)
    f32x4 s[4] = {};
#pragma unroll
    for (int kk = 0; kk < 2; ++kk)
#pragma unroll
      for (int nb = 0; nb < 4; ++nb) {
        bf16x8 kf = *(const bf16x8*)&Kh[(size_t)(kv0 + nb * 16 + c16) * 64 + kk * 32 + 8 * g];
        s[nb] = __builtin_amdgcn_mfma_f32_16x16x32_bf16(qf[kk], kf, s[nb], 0, 0, 0);
      }

    // causal mask: only the diagonal tile needs it
    if (kv0 == q0) {
#pragma unroll
      for (int nb = 0; nb < 4; ++nb) {
        int kvg = kv0 + nb * 16 + c16;
#pragma unroll
        for (int r = 0; r < 4; ++r) {
          int qg = q0 + w * 16 + g * 4 + r;
          if (kvg > qg) s[nb][r] = NEG_INF;
        }
      }
    }

    // row max (raw domain; scale folded into exp arg)
    float rm[4];
#pragma unroll
    for (int r = 0; r < 4; ++r) {
      float v = fmaxf(fmaxf(s[0][r], s[1][r]), fmaxf(s[2][r], s[3][r]));
#pragma unroll
      for (int off = 1; off < 16; off <<= 1) v = fmaxf(v, __shfl_xor(v, off));
      rm[r] = v;
    }
    // defer-max: skip rescale when no row max grew (wave-uniform branch)
    bool grow = (rm[0] > m[0]) | (rm[1] > m[1]) | (rm[2] > m[2]) | (rm[3] > m[3]);
    if (__any(grow)) {
#pragma unroll
      for (int r = 0; r < 4; ++r) {
        float mn = fmaxf(m[r], rm[r]);
        float alpha = __expf((m[r] - mn) * 0.125f);
        lsum[r] *= alpha;
#pragma unroll
        for (int nb = 0; nb < 4; ++nb) o[nb][r] *= alpha;
        m[r] = mn;
      }
    }
    // P = exp((s - m) * 0.125), row sums
#pragma unroll
    for (int r = 0; r < 4; ++r) {
      float rs = 0.f;
#pragma unroll
      for (int nb = 0; nb < 4; ++nb) {
        float p = __expf((s[nb][r] - m[r]) * 0.125f);
        s[nb][r] = p;
        rs += p;
      }
#pragma unroll
      for (int off = 1; off < 16; off <<= 1) rs += __shfl_xor(rs, off);
      lsum[r] += rs;
    }

    // P -> wave-private LDS (swizzled); no barrier needed
#pragma unroll
    for (int nb = 0; nb < 4; ++nb)
#pragma unroll
      for (int r = 0; r < 4; ++r) {
        int row = g * 4 + r;
        int col = nb * 16 + c16;
        Pw[row * 64 + (((col >> 3) ^ (row & 7)) << 3) + (col & 7)] = f2bf(s[nb][r]);
      }

    // PV: A = P (LDS), B = V^T rows direct from global
#pragma unroll
    for (int kk = 0; kk < 2; ++kk) {
      bf16x8 pf = *(const bf16x8*)&Pw[c16 * 64 + (((kk * 4 + g) ^ (c16 & 7)) << 3)];
#pragma unroll
      for (int nb = 0; nb < 4; ++nb) {
        bf16x8 vf = *(const bf16x8*)&Vh[(size_t)(nb * 16 + c16) * 2048 + kv0 + kk * 32 + 8 * g];
        o[nb] = __builtin_amdgcn_mfma_f32_16x16x32_bf16(pf, vf, o[nb], 0, 0, 0);
      }
    }
  }

  // epilogue: y[b][t][h*64+d] bf16
  size_t yb = ((size_t)(hd >> 4) * 2048) * 1024 + (size_t)(hd & 15) * 64;
#pragma unroll
  for (int nb = 0; nb < 4; ++nb)
#pragma unroll
    for (int r = 0; r < 4; ++r) {
      int row = q0 + w * 16 + g * 4 + r;
      int col = nb * 16 + c16;
      Y[yb + (size_t)row * 1024 + col] = f2bf(o[nb][r] / lsum[r]);
    }
}

extern "C" void kernel_launch(void* const* d_in, const int* in_sizes, int n_in,
                              void* d_out, int out_size, void* d_ws, size_t ws_size,
                              hipStream_t stream) {
  (void)in_sizes; (void)n_in; (void)out_size; (void)ws_size;
  const float* x      = (const float*)d_in[0];
  const float* W_attn = (const float*)d_in[1];
  const float* b_attn = (const float*)d_in[2];
  const float* W_proj = (const float*)d_in[3];
  const float* b_proj = (const float*)d_in[4];
  float* out = (float*)d_out;

  char* ws = (char*)d_ws;
  u16* Xb  = (u16*)(ws);                                   // 8192*1024 bf16 (reused as Yb)
  u16* Wt  = (u16*)(ws + 16777216);                        // 3072*1024 bf16
  u16* Wpt = (u16*)(ws + 16777216 + 6291456);              // 1024*1024 bf16
  u16* QKV = (u16*)(ws + 16777216 + 6291456 + 2097152);    // 3 * 8388608 bf16
  u16* Yb  = Xb;

  conv_x_kernel<<<2048, 256, 0, stream>>>((const float4*)x, (u16x4*)Xb, 2097152);
  transpose_bf16<<<dim3(48, 16), 256, 0, stream>>>(W_attn, Wt, 1024, 3072);
  transpose_bf16<<<dim3(16, 16), 256, 0, stream>>>(W_proj, Wpt, 1024, 1024);
  gemm_bf16<0><<<1536, 256, 0, stream>>>(Xb, Wt, b_attn, nullptr, QKV, 24);
  attn_fwd<<<2048, 256, 0, stream>>>(QKV, QKV + BHTD, QKV + 2 * BHTD, Yb);
  gemm_bf16<1><<<512, 256, 0, stream>>>(Yb, Wpt, b_proj, out, nullptr, 8);
}

// Round 3
// 267.997 us; speedup vs baseline: 1.7121x; 1.3998x over previous
//
#include <hip/hip_runtime.h>

typedef unsigned short u16;
typedef unsigned int u32;
typedef __bf16 bf16x8 __attribute__((ext_vector_type(8)));
typedef u16 u16x8 __attribute__((ext_vector_type(8)));
typedef u16 u16x4 __attribute__((ext_vector_type(4)));
typedef float f32x4 __attribute__((ext_vector_type(4)));
typedef float f32x16 __attribute__((ext_vector_type(16)));

#define BHTD 8388608  // 4*16*2048*64 elements per Q/K/V tensor
#define QSCALE 0.18033688f  // 0.125 * log2(e): softmax in exp2 domain

__device__ __forceinline__ u16 f2bf(float f) {
  union { float f; u32 u; } x; x.f = f;
  u32 r = (x.u + 0x7FFFu + ((x.u >> 16) & 1u)) >> 16;
  return (u16)r;
}

__device__ __forceinline__ u32 cvt_pk_bf16(float lo, float hi) {
  u32 r;
  asm("v_cvt_pk_bf16_f32 %0, %1, %2" : "=v"(r) : "v"(lo), "v"(hi));
  return r;
}

__device__ __forceinline__ void async_copy16(const u16* gsrc, u16* ldst) {
  __builtin_amdgcn_global_load_lds(
      (const __attribute__((address_space(1))) void*)gsrc,
      (__attribute__((address_space(3))) void*)ldst, 16, 0, 0);
}

// ---------------- fp32 -> bf16 elementwise convert ----------------
__global__ __launch_bounds__(256) void conv_x_kernel(const float4* __restrict__ in,
                                                     u16x4* __restrict__ out, int n4) {
  int i = blockIdx.x * 256 + threadIdx.x;
  int stride = gridDim.x * 256;
  for (; i < n4; i += stride) {
    float4 v = in[i];
    u16x4 o = { f2bf(v.x), f2bf(v.y), f2bf(v.z), f2bf(v.w) };
    out[i] = o;
  }
}

// ---------------- fp32 [K][N] -> bf16 transposed [N][K] ----------------
__global__ __launch_bounds__(256) void transpose_bf16(const float* __restrict__ W,
                                                      u16* __restrict__ Wt, int K, int N) {
  __shared__ float t[64][65];
  int c0 = blockIdx.x * 64;  // col block (N)
  int r0 = blockIdx.y * 64;  // row block (K)
  int c = threadIdx.x & 63;
  int r4 = threadIdx.x >> 6;
#pragma unroll
  for (int j = 0; j < 16; ++j) {
    int r = j * 4 + r4;
    t[r][c] = W[(size_t)(r0 + r) * N + (c0 + c)];
  }
  __syncthreads();
#pragma unroll
  for (int j = 0; j < 16; ++j) {
    int n = j * 4 + r4;
    Wt[(size_t)(c0 + n) * K + (r0 + c)] = f2bf(t[c][n]);
  }
}

// ---------------- bf16 GEMM: C[M][N] = A[M][1024] * Bt[N][1024]^T + bias ----------------
// 128x128 tile, 4 waves (2x2), BK=64, global_load_lds staging with XOR slot swizzle.
// MODE 0: scatter to QKV; Q (pre-scaled by QSCALE),K as [B][H][T][64], V TRANSPOSED
// as [B][H][64][T] (bf16).  MODE 1: fp32 out [M][1024].
template <int MODE>
__global__ __launch_bounds__(256) void gemm_bf16(const u16* __restrict__ A,
                                                 const u16* __restrict__ Bt,
                                                 const float* __restrict__ bias,
                                                 float* __restrict__ outp,
                                                 u16* __restrict__ qkv, int grid_n) {
  __shared__ __attribute__((aligned(16))) u16 A_lds[128 * 64];
  __shared__ __attribute__((aligned(16))) u16 B_lds[128 * 64];
  const int tid = threadIdx.x;
  const int lane = tid & 63, wave = tid >> 6;
  const int wr = wave >> 1, wc = wave & 1;
  const int bn = blockIdx.x % grid_n, bm = blockIdx.x / grid_n;
  const int m0 = bm * 128, n0 = bn * 128;
  const int g = lane >> 4, c16 = lane & 15;
  const int lrow = lane >> 3, lslot = lane & 7;

  f32x4 acc[4][4] = {};

  for (int kt = 0; kt < 16; ++kt) {
#pragma unroll
    for (int i = 0; i < 4; ++i) {
      int mloc = (wave * 4 + i) * 8 + lrow;
      int col = kt * 64 + ((lslot ^ (mloc & 7)) << 3);  // pre-swizzled global source
      async_copy16(&A[(size_t)(m0 + mloc) * 1024 + col], &A_lds[(wave * 4 + i) * 512]);
      async_copy16(&Bt[(size_t)(n0 + mloc) * 1024 + col], &B_lds[(wave * 4 + i) * 512]);
    }
    __syncthreads();  // compiler drains vmcnt before barrier
#pragma unroll
    for (int kk = 0; kk < 2; ++kk) {
      bf16x8 af[4], bfr[4];
#pragma unroll
      for (int mb = 0; mb < 4; ++mb) {
        int row = wr * 64 + mb * 16 + c16;
        int slot = (kk * 4 + g) ^ (row & 7);
        af[mb] = *(const bf16x8*)&A_lds[row * 64 + slot * 8];
        int rowb = wc * 64 + mb * 16 + c16;
        int slotb = (kk * 4 + g) ^ (rowb & 7);
        bfr[mb] = *(const bf16x8*)&B_lds[rowb * 64 + slotb * 8];
      }
#pragma unroll
      for (int mb = 0; mb < 4; ++mb)
#pragma unroll
        for (int nb = 0; nb < 4; ++nb)
          acc[mb][nb] = __builtin_amdgcn_mfma_f32_16x16x32_bf16(af[mb], bfr[nb], acc[mb][nb], 0, 0, 0);
    }
    __syncthreads();
  }

  float bv[4];
#pragma unroll
  for (int nb = 0; nb < 4; ++nb) bv[nb] = bias[n0 + wc * 64 + nb * 16 + c16];

#pragma unroll
  for (int mb = 0; mb < 4; ++mb) {
    int row0 = m0 + wr * 64 + mb * 16 + g * 4;
#pragma unroll
    for (int nb = 0; nb < 4; ++nb) {
      int col = n0 + wc * 64 + nb * 16 + c16;
      float bvn = bv[nb];
      if (MODE == 0) {
        int sel = col >> 10, ci = col & 1023;
        int hh = ci >> 6, d = ci & 63;
        int bb = row0 >> 11, t0 = row0 & 2047;
        float qs = (sel == 0) ? QSCALE : 1.0f;
        if (sel == 2) {
          // V transposed: [bh][d][t], 4 consecutive t -> one 8B store
          u16x4 pk;
#pragma unroll
          for (int r = 0; r < 4; ++r) pk[r] = f2bf(acc[mb][nb][r] + bvn);
          *(u16x4*)&qkv[(size_t)2 * BHTD + (((size_t)(bb * 16 + hh) * 64 + d) << 11) + t0] = pk;
        } else {
#pragma unroll
          for (int r = 0; r < 4; ++r) {
            qkv[(size_t)sel * BHTD + (((size_t)(bb * 16 + hh) * 2048 + t0 + r) << 6) + d] =
                f2bf((acc[mb][nb][r] + bvn) * qs);
          }
        }
      } else {
#pragma unroll
        for (int r = 0; r < 4; ++r)
          outp[((size_t)(row0 + r) << 10) + col] = acc[mb][nb][r] + bvn;
      }
    }
  }
}

// ---------------- causal flash attention, swapped-operand 32x32x16, zero LDS ----------------
// 1 block = (qt, b, h): 128 q rows, 4 waves x 32 rows. Swapped QK^T: S^T[kv][q] with
// q = lane&31 -> softmax fully per-lane + one shfl_xor(32). PV as O^T = V^T * P^T:
// V^T rows direct from global (V stored [bh][d][t]), P^T built in-register via
// cvt_pk_bf16 + shfl_xor(32). No LDS, no barriers.
__global__ __launch_bounds__(256) void attn_fwd(const u16* __restrict__ Q,
                                                const u16* __restrict__ K,
                                                const u16* __restrict__ VT,
                                                u16* __restrict__ Y) {
  const float NEG_INF = -__builtin_inff();
  int bid = blockIdx.x;
  int qt = bid >> 6, hd = bid & 63;  // hd&7 = XCD -> per-XCD K/V working set = 8 heads
  size_t hb = (size_t)hd * (2048 * 64);
  const u16* Qh = Q + hb;
  const u16* Kh = K + hb;
  const u16* Vh = VT + hb;  // [64][2048]
  int tid = threadIdx.x, lane = tid & 63, w = tid >> 6;
  int c32 = lane & 31, h = lane >> 5;
  int qw0 = qt * 128 + w * 32;
  int qrow = qw0 + c32;   // this lane's q row
  int qend = qw0 + 32;    // wave-local early exit

  bf16x8 qf[4];  // Q[qrow][dk*16 + 8h .. +7], pre-scaled by QSCALE
#pragma unroll
  for (int dk = 0; dk < 4; ++dk)
    qf[dk] = *(const bf16x8*)&Qh[(size_t)qrow * 64 + dk * 16 + 8 * h];

  float m = NEG_INF, l = 0.f;
  f32x16 o0 = {}, o1 = {};  // O^T[d = db*32 + pat][q=c32]

  for (int kv0 = 0; kv0 < qend; kv0 += 64) {
    // ---- S^T = K * Q^T : A=K rows (kv), B=Q^T cols (q) ----
    bf16x8 kf[2][4];
#pragma unroll
    for (int kb = 0; kb < 2; ++kb)
#pragma unroll
      for (int dk = 0; dk < 4; ++dk)
        kf[kb][dk] = *(const bf16x8*)&Kh[(size_t)(kv0 + kb * 32 + c32) * 64 + dk * 16 + 8 * h];
    f32x16 s0 = {}, s1 = {};
#pragma unroll
    for (int dk = 0; dk < 4; ++dk) {
      s0 = __builtin_amdgcn_mfma_f32_32x32x16_bf16(kf[0][dk], qf[dk], s0, 0, 0, 0);
      s1 = __builtin_amdgcn_mfma_f32_32x32x16_bf16(kf[1][dk], qf[dk], s1, 0, 0, 0);
    }

    // causal mask: only the last tile of each wave needs it
    if (kv0 + 64 >= qend) {
      int kvb = kv0 + 4 * h;
#pragma unroll
      for (int reg = 0; reg < 16; ++reg) {
        int kvl = kvb + 8 * (reg >> 2) + (reg & 3);  // kv of s0[reg]
        if (kvl > qrow) s0[reg] = NEG_INF;
        if (kvl + 32 > qrow) s1[reg] = NEG_INF;
      }
    }

    // ---- online softmax: per-lane row, one cross-lane op ----
    float rm = s0[0];
#pragma unroll
    for (int i = 1; i < 16; ++i) rm = fmaxf(rm, s0[i]);
#pragma unroll
    for (int i = 0; i < 16; ++i) rm = fmaxf(rm, s1[i]);
    rm = fmaxf(rm, __shfl_xor(rm, 32));
    if (__any(rm > m)) {  // defer-max: skip rescale when no row grew
      float mn = fmaxf(m, rm);
      float alpha = __builtin_exp2f(m - mn);
      l *= alpha;
      o0 *= alpha;
      o1 *= alpha;
      m = mn;
    }
    float rs = 0.f;
#pragma unroll
    for (int i = 0; i < 16; ++i) { s0[i] = __builtin_exp2f(s0[i] - m); rs += s0[i]; }
#pragma unroll
    for (int i = 0; i < 16; ++i) { s1[i] = __builtin_exp2f(s1[i] - m); rs += s1[i]; }
    rs += __shfl_xor(rs, 32);
    l += rs;

    // ---- P^T B-frags in-register: pack pairs to bf16, exchange halves (xor 32) ----
    u32 pw[2][8], pt[2][8];
#pragma unroll
    for (int mm = 0; mm < 8; ++mm) {
      pw[0][mm] = cvt_pk_bf16(s0[2 * mm], s0[2 * mm + 1]);
      pw[1][mm] = cvt_pk_bf16(s1[2 * mm], s1[2 * mm + 1]);
    }
#pragma unroll
    for (int kb = 0; kb < 2; ++kb)
#pragma unroll
      for (int mm = 0; mm < 8; ++mm)
        pt[kb][mm] = (u32)__shfl_xor((int)pw[kb][mm], 32);

    // ---- O^T += V^T * P^T over 4 kv-chunks of 16 ----
#pragma unroll
    for (int c = 0; c < 4; ++c) {
      const int kb = c >> 1, a = 4 * (c & 1);
      union { u32 u[4]; bf16x8 v; } pf;
      pf.u[0] = h ? pt[kb][a + 2] : pw[kb][a + 0];
      pf.u[1] = h ? pt[kb][a + 3] : pw[kb][a + 1];
      pf.u[2] = h ? pw[kb][a + 2] : pt[kb][a + 0];
      pf.u[3] = h ? pw[kb][a + 3] : pt[kb][a + 1];
      bf16x8 vf0 = *(const bf16x8*)&Vh[(size_t)(c32) * 2048 + kv0 + c * 16 + 8 * h];
      bf16x8 vf1 = *(const bf16x8*)&Vh[(size_t)(32 + c32) * 2048 + kv0 + c * 16 + 8 * h];
      o0 = __builtin_amdgcn_mfma_f32_32x32x16_bf16(vf0, pf.v, o0, 0, 0, 0);
      o1 = __builtin_amdgcn_mfma_f32_32x32x16_bf16(vf1, pf.v, o1, 0, 0, 0);
    }
  }

  // epilogue: lane owns row q=qrow; O^T reg (db,rq,j) -> d = db*32 + 8*rq + 4*h + j
  float inv = 1.0f / l;
  size_t yb = (size_t)(hd >> 4) * (2048 * 1024) + (size_t)(hd & 15) * 64 + (size_t)qrow * 1024;
#pragma unroll
  for (int db = 0; db < 2; ++db)
#pragma unroll
    for (int rq = 0; rq < 4; ++rq) {
      u16x4 pk;
#pragma unroll
      for (int j = 0; j < 4; ++j)
        pk[j] = f2bf((db ? o1[rq * 4 + j] : o0[rq * 4 + j]) * inv);
      *(u16x4*)&Y[yb + db * 32 + 8 * rq + 4 * h] = pk;
    }
}

extern "C" void kernel_launch(void* const* d_in, const int* in_sizes, int n_in,
                              void* d_out, int out_size, void* d_ws, size_t ws_size,
                              hipStream_t stream) {
  (void)in_sizes; (void)n_in; (void)out_size; (void)ws_size;
  const float* x      = (const float*)d_in[0];
  const float* W_attn = (const float*)d_in[1];
  const float* b_attn = (const float*)d_in[2];
  const float* W_proj = (const float*)d_in[3];
  const float* b_proj = (const float*)d_in[4];
  float* out = (float*)d_out;

  char* ws = (char*)d_ws;
  u16* Xb  = (u16*)(ws);                                   // 8192*1024 bf16 (reused as Yb)
  u16* Wt  = (u16*)(ws + 16777216);                        // 3072*1024 bf16
  u16* Wpt = (u16*)(ws + 16777216 + 6291456);              // 1024*1024 bf16
  u16* QKV = (u16*)(ws + 16777216 + 6291456 + 2097152);    // 3 * 8388608 bf16
  u16* Yb  = Xb;

  conv_x_kernel<<<2048, 256, 0, stream>>>((const float4*)x, (u16x4*)Xb, 2097152);
  transpose_bf16<<<dim3(48, 16), 256, 0, stream>>>(W_attn, Wt, 1024, 3072);
  transpose_bf16<<<dim3(16, 16), 256, 0, stream>>>(W_proj, Wpt, 1024, 1024);
  gemm_bf16<0><<<1536, 256, 0, stream>>>(Xb, Wt, b_attn, nullptr, QKV, 24);
  attn_fwd<<<1024, 256, 0, stream>>>(QKV, QKV + BHTD, QKV + 2 * BHTD, Yb);
  gemm_bf16<1><<<512, 256, 0, stream>>>(Yb, Wpt, b_proj, out, nullptr, 8);
}

// Round 4
// 246.753 us; speedup vs baseline: 1.8595x; 1.0861x over previous
//
#include <hip/hip_runtime.h>

typedef unsigned short u16;
typedef unsigned int u32;
typedef __bf16 bf16x8 __attribute__((ext_vector_type(8)));
typedef u16 u16x8 __attribute__((ext_vector_type(8)));
typedef u16 u16x4 __attribute__((ext_vector_type(4)));
typedef float f32x4 __attribute__((ext_vector_type(4)));
typedef float f32x16 __attribute__((ext_vector_type(16)));

#define BHTD 8388608  // 4*16*2048*64 elements per Q/K/V tensor
#define QSCALE 0.18033688f  // 0.125 * log2(e): softmax in exp2 domain

__device__ __forceinline__ u16 f2bf(float f) {
  union { float f; u32 u; } x; x.f = f;
  u32 r = (x.u + 0x7FFFu + ((x.u >> 16) & 1u)) >> 16;
  return (u16)r;
}

__device__ __forceinline__ u32 cvt_pk_bf16(float lo, float hi) {
  u32 r;
  asm("v_cvt_pk_bf16_f32 %0, %1, %2" : "=v"(r) : "v"(lo), "v"(hi));
  return r;
}

// v_permlane32_swap_b32: x.hi32lanes <-> y.lo32lanes (both updated in place).
__device__ __forceinline__ void permlane32_swap(u32& x, u32& y) {
  asm("v_permlane32_swap_b32 %0, %1" : "+v"(x), "+v"(y));
}

__device__ __forceinline__ void async_copy16(const u16* gsrc, u16* ldst) {
  __builtin_amdgcn_global_load_lds(
      (const __attribute__((address_space(1))) void*)gsrc,
      (__attribute__((address_space(3))) void*)ldst, 16, 0, 0);
}

// ---------------- fp32 -> bf16 elementwise convert ----------------
__global__ __launch_bounds__(256) void conv_x_kernel(const float4* __restrict__ in,
                                                     u16x4* __restrict__ out, int n4) {
  int i = blockIdx.x * 256 + threadIdx.x;
  int stride = gridDim.x * 256;
  for (; i < n4; i += stride) {
    float4 v = in[i];
    u16x4 o = { f2bf(v.x), f2bf(v.y), f2bf(v.z), f2bf(v.w) };
    out[i] = o;
  }
}

// ---------------- fp32 [K][N] -> bf16 transposed [N][K] ----------------
__global__ __launch_bounds__(256) void transpose_bf16(const float* __restrict__ W,
                                                      u16* __restrict__ Wt, int K, int N) {
  __shared__ float t[64][65];
  int c0 = blockIdx.x * 64;  // col block (N)
  int r0 = blockIdx.y * 64;  // row block (K)
  int c = threadIdx.x & 63;
  int r4 = threadIdx.x >> 6;
#pragma unroll
  for (int j = 0; j < 16; ++j) {
    int r = j * 4 + r4;
    t[r][c] = W[(size_t)(r0 + r) * N + (c0 + c)];
  }
  __syncthreads();
#pragma unroll
  for (int j = 0; j < 16; ++j) {
    int n = j * 4 + r4;
    Wt[(size_t)(c0 + n) * K + (r0 + c)] = f2bf(t[c][n]);
  }
}

// ---------------- bf16 GEMM: C[M][N] = A[M][1024] * Bt[N][1024]^T + bias ----------------
// 128x128 tile, 4 waves (2x2), BK=64, global_load_lds staging with XOR slot swizzle.
// MODE 0: scatter to QKV; Q (pre-scaled by QSCALE),K as [B][H][T][64], V TRANSPOSED
// as [B][H][64][T] (bf16).  MODE 1: fp32 out [M][1024].
template <int MODE>
__global__ __launch_bounds__(256) void gemm_bf16(const u16* __restrict__ A,
                                                 const u16* __restrict__ Bt,
                                                 const float* __restrict__ bias,
                                                 float* __restrict__ outp,
                                                 u16* __restrict__ qkv, int grid_n) {
  __shared__ __attribute__((aligned(16))) u16 A_lds[128 * 64];
  __shared__ __attribute__((aligned(16))) u16 B_lds[128 * 64];
  const int tid = threadIdx.x;
  const int lane = tid & 63, wave = tid >> 6;
  const int wr = wave >> 1, wc = wave & 1;
  const int bn = blockIdx.x % grid_n, bm = blockIdx.x / grid_n;
  const int m0 = bm * 128, n0 = bn * 128;
  const int g = lane >> 4, c16 = lane & 15;
  const int lrow = lane >> 3, lslot = lane & 7;

  f32x4 acc[4][4] = {};

  for (int kt = 0; kt < 16; ++kt) {
#pragma unroll
    for (int i = 0; i < 4; ++i) {
      int mloc = (wave * 4 + i) * 8 + lrow;
      int col = kt * 64 + ((lslot ^ (mloc & 7)) << 3);  // pre-swizzled global source
      async_copy16(&A[(size_t)(m0 + mloc) * 1024 + col], &A_lds[(wave * 4 + i) * 512]);
      async_copy16(&Bt[(size_t)(n0 + mloc) * 1024 + col], &B_lds[(wave * 4 + i) * 512]);
    }
    __syncthreads();  // compiler drains vmcnt before barrier
#pragma unroll
    for (int kk = 0; kk < 2; ++kk) {
      bf16x8 af[4], bfr[4];
#pragma unroll
      for (int mb = 0; mb < 4; ++mb) {
        int row = wr * 64 + mb * 16 + c16;
        int slot = (kk * 4 + g) ^ (row & 7);
        af[mb] = *(const bf16x8*)&A_lds[row * 64 + slot * 8];
        int rowb = wc * 64 + mb * 16 + c16;
        int slotb = (kk * 4 + g) ^ (rowb & 7);
        bfr[mb] = *(const bf16x8*)&B_lds[rowb * 64 + slotb * 8];
      }
#pragma unroll
      for (int mb = 0; mb < 4; ++mb)
#pragma unroll
        for (int nb = 0; nb < 4; ++nb)
          acc[mb][nb] = __builtin_amdgcn_mfma_f32_16x16x32_bf16(af[mb], bfr[nb], acc[mb][nb], 0, 0, 0);
    }
    __syncthreads();
  }

  float bv[4];
#pragma unroll
  for (int nb = 0; nb < 4; ++nb) bv[nb] = bias[n0 + wc * 64 + nb * 16 + c16];

#pragma unroll
  for (int mb = 0; mb < 4; ++mb) {
    int row0 = m0 + wr * 64 + mb * 16 + g * 4;
#pragma unroll
    for (int nb = 0; nb < 4; ++nb) {
      int col = n0 + wc * 64 + nb * 16 + c16;
      float bvn = bv[nb];
      if (MODE == 0) {
        int sel = col >> 10, ci = col & 1023;
        int hh = ci >> 6, d = ci & 63;
        int bb = row0 >> 11, t0 = row0 & 2047;
        float qs = (sel == 0) ? QSCALE : 1.0f;
        if (sel == 2) {
          // V transposed: [bh][d][t], 4 consecutive t -> one 8B store
          u16x4 pk;
#pragma unroll
          for (int r = 0; r < 4; ++r) pk[r] = f2bf(acc[mb][nb][r] + bvn);
          *(u16x4*)&qkv[(size_t)2 * BHTD + (((size_t)(bb * 16 + hh) * 64 + d) << 11) + t0] = pk;
        } else {
#pragma unroll
          for (int r = 0; r < 4; ++r) {
            qkv[(size_t)sel * BHTD + (((size_t)(bb * 16 + hh) * 2048 + t0 + r) << 6) + d] =
                f2bf((acc[mb][nb][r] + bvn) * qs);
          }
        }
      } else {
#pragma unroll
        for (int r = 0; r < 4; ++r)
          outp[((size_t)(row0 + r) << 10) + col] = acc[mb][nb][r] + bvn;
      }
    }
  }
}

// ---------------- causal flash attention, swapped-operand 32x32x16, zero LDS ----------------
// 1 block = (qt, b, h) with LPT ordering (heaviest qt first). 4 waves x 32 q rows.
// K fragments software-pipelined (next tile's loads issue right after QK consumes
// current); V loads issue at loop top, consumed at PV after softmax. P^T built
// in-register via cvt_pk_bf16 + v_permlane32_swap. No LDS, no barriers.
__global__ __launch_bounds__(256) void attn_fwd(const u16* __restrict__ Q,
                                                const u16* __restrict__ K,
                                                const u16* __restrict__ VT,
                                                u16* __restrict__ Y) {
  const float NEG_INF = -__builtin_inff();
  int bid = blockIdx.x;
  int qt = 15 - (bid >> 6);          // LPT: heavy blocks dispatch first
  int hd = bid & 63;
  size_t hb = (size_t)hd * (2048 * 64);
  const u16* Qh = Q + hb;
  const u16* Kh = K + hb;
  const u16* Vh = VT + hb;  // [64][2048]
  int tid = threadIdx.x, lane = tid & 63, w = tid >> 6;
  int c32 = lane & 31, h = lane >> 5;
  int qw0 = qt * 128 + w * 32;
  int qrow = qw0 + c32;   // this lane's q row
  int qend = qw0 + 32;    // wave-local early exit

  bf16x8 qf[4];  // Q[qrow][dk*16 + 8h .. +7], pre-scaled by QSCALE
#pragma unroll
  for (int dk = 0; dk < 4; ++dk)
    qf[dk] = *(const bf16x8*)&Qh[(size_t)qrow * 64 + dk * 16 + 8 * h];

  float m = NEG_INF, l = 0.f;
  f32x16 o0 = {}, o1 = {};  // O^T[d = db*32 + pat][q=c32]

  // prefetch K tile 0
  bf16x8 kf[2][4];
#pragma unroll
  for (int kb = 0; kb < 2; ++kb)
#pragma unroll
    for (int dk = 0; dk < 4; ++dk)
      kf[kb][dk] = *(const bf16x8*)&Kh[(size_t)(kb * 32 + c32) * 64 + dk * 16 + 8 * h];

  for (int kv0 = 0; kv0 < qend; kv0 += 64) {
    // V loads for the current tile (independent; consumed after softmax)
    bf16x8 vf0[4], vf1[4];
#pragma unroll
    for (int c = 0; c < 4; ++c) {
      vf0[c] = *(const bf16x8*)&Vh[(size_t)(c32) * 2048 + kv0 + c * 16 + 8 * h];
      vf1[c] = *(const bf16x8*)&Vh[(size_t)(32 + c32) * 2048 + kv0 + c * 16 + 8 * h];
    }

    // ---- S^T = K * Q^T ----
    f32x16 s0 = {}, s1 = {};
#pragma unroll
    for (int dk = 0; dk < 4; ++dk) {
      s0 = __builtin_amdgcn_mfma_f32_32x32x16_bf16(kf[0][dk], qf[dk], s0, 0, 0, 0);
      s1 = __builtin_amdgcn_mfma_f32_32x32x16_bf16(kf[1][dk], qf[dk], s1, 0, 0, 0);
    }

    // prefetch next K tile (overwrites kf; latency hidden under softmax+PV)
    if (kv0 + 64 < qend) {
#pragma unroll
      for (int kb = 0; kb < 2; ++kb)
#pragma unroll
        for (int dk = 0; dk < 4; ++dk)
          kf[kb][dk] =
              *(const bf16x8*)&Kh[(size_t)(kv0 + 64 + kb * 32 + c32) * 64 + dk * 16 + 8 * h];
    }

    // causal mask: only the last tile of each wave needs it
    if (kv0 + 64 >= qend) {
      int kvb = kv0 + 4 * h;
#pragma unroll
      for (int reg = 0; reg < 16; ++reg) {
        int kvl = kvb + 8 * (reg >> 2) + (reg & 3);  // kv of s0[reg]
        if (kvl > qrow) s0[reg] = NEG_INF;
        if (kvl + 32 > qrow) s1[reg] = NEG_INF;
      }
    }

    // ---- online softmax: per-lane row, tree reductions ----
    float t[16];
#pragma unroll
    for (int i = 0; i < 16; ++i) t[i] = fmaxf(s0[i], s1[i]);
#pragma unroll
    for (int st = 8; st >= 1; st >>= 1)
#pragma unroll
      for (int i = 0; i < 8; ++i)
        if (i < st) t[i] = fmaxf(t[i], t[i + st]);
    float rm = t[0];
    rm = fmaxf(rm, __shfl_xor(rm, 32));
    if (__any(rm - m > 8.f)) {  // defer-max: rescale only when a row grew >2^8
      float mn = fmaxf(m, rm);
      float alpha = __builtin_exp2f(m - mn);
      l *= alpha;
      o0 *= alpha;
      o1 *= alpha;
      m = mn;
    }
#pragma unroll
    for (int i = 0; i < 16; ++i) s0[i] = __builtin_exp2f(s0[i] - m);
#pragma unroll
    for (int i = 0; i < 16; ++i) s1[i] = __builtin_exp2f(s1[i] - m);
#pragma unroll
    for (int i = 0; i < 16; ++i) t[i] = s0[i] + s1[i];
#pragma unroll
    for (int st = 8; st >= 1; st >>= 1)
#pragma unroll
      for (int i = 0; i < 8; ++i)
        if (i < st) t[i] += t[i + st];
    float rs = t[0];
    rs += __shfl_xor(rs, 32);
    l += rs;

    // ---- P^T: pack pairs to bf16, half-exchange via permlane32_swap ----
    u32 pw0[8], pw1[8];
#pragma unroll
    for (int mm = 0; mm < 8; ++mm) {
      pw0[mm] = cvt_pk_bf16(s0[2 * mm], s0[2 * mm + 1]);
      pw1[mm] = cvt_pk_bf16(s1[2 * mm], s1[2 * mm + 1]);
    }
    permlane32_swap(pw0[0], pw0[2]); permlane32_swap(pw0[1], pw0[3]);
    permlane32_swap(pw0[4], pw0[6]); permlane32_swap(pw0[5], pw0[7]);
    permlane32_swap(pw1[0], pw1[2]); permlane32_swap(pw1[1], pw1[3]);
    permlane32_swap(pw1[4], pw1[6]); permlane32_swap(pw1[5], pw1[7]);

    // ---- O^T += V^T * P^T over 4 kv-chunks of 16 ----
#pragma unroll
    for (int c = 0; c < 4; ++c) {
      const u32* pp = (c >> 1) ? pw1 : pw0;
      const int a = 4 * (c & 1);
      union { u32 u[4]; bf16x8 v; } pf;
      pf.u[0] = pp[a + 0];
      pf.u[1] = pp[a + 1];
      pf.u[2] = pp[a + 2];
      pf.u[3] = pp[a + 3];
      o0 = __builtin_amdgcn_mfma_f32_32x32x16_bf16(vf0[c], pf.v, o0, 0, 0, 0);
      o1 = __builtin_amdgcn_mfma_f32_32x32x16_bf16(vf1[c], pf.v, o1, 0, 0, 0);
    }
  }

  // epilogue: lane owns row q=qrow; O^T reg (db,rq,j) -> d = db*32 + 8*rq + 4*h + j
  float inv = 1.0f / l;
  size_t yb = (size_t)(hd >> 4) * (2048 * 1024) + (size_t)(hd & 15) * 64 + (size_t)qrow * 1024;
#pragma unroll
  for (int db = 0; db < 2; ++db)
#pragma unroll
    for (int rq = 0; rq < 4; ++rq) {
      u16x4 pk;
#pragma unroll
      for (int j = 0; j < 4; ++j)
        pk[j] = f2bf((db ? o1[rq * 4 + j] : o0[rq * 4 + j]) * inv);
      *(u16x4*)&Y[yb + db * 32 + 8 * rq + 4 * h] = pk;
    }
}

extern "C" void kernel_launch(void* const* d_in, const int* in_sizes, int n_in,
                              void* d_out, int out_size, void* d_ws, size_t ws_size,
                              hipStream_t stream) {
  (void)in_sizes; (void)n_in; (void)out_size; (void)ws_size;
  const float* x      = (const float*)d_in[0];
  const float* W_attn = (const float*)d_in[1];
  const float* b_attn = (const float*)d_in[2];
  const float* W_proj = (const float*)d_in[3];
  const float* b_proj = (const float*)d_in[4];
  float* out = (float*)d_out;

  char* ws = (char*)d_ws;
  u16* Xb  = (u16*)(ws);                                   // 8192*1024 bf16 (reused as Yb)
  u16* Wt  = (u16*)(ws + 16777216);                        // 3072*1024 bf16
  u16* Wpt = (u16*)(ws + 16777216 + 6291456);              // 1024*1024 bf16
  u16* QKV = (u16*)(ws + 16777216 + 6291456 + 2097152);    // 3 * 8388608 bf16
  u16* Yb  = Xb;

  conv_x_kernel<<<2048, 256, 0, stream>>>((const float4*)x, (u16x4*)Xb, 2097152);
  transpose_bf16<<<dim3(48, 16), 256, 0, stream>>>(W_attn, Wt, 1024, 3072);
  transpose_bf16<<<dim3(16, 16), 256, 0, stream>>>(W_proj, Wpt, 1024, 1024);
  gemm_bf16<0><<<1536, 256, 0, stream>>>(Xb, Wt, b_attn, nullptr, QKV, 24);
  attn_fwd<<<1024, 256, 0, stream>>>(QKV, QKV + BHTD, QKV + 2 * BHTD, Yb);
  gemm_bf16<1><<<512, 256, 0, stream>>>(Yb, Wpt, b_proj, out, nullptr, 8);
}

// Round 5
// 186.015 us; speedup vs baseline: 2.4667x; 1.3265x over previous
//
#include <hip/hip_runtime.h>

typedef unsigned short u16;
typedef unsigned int u32;
typedef __bf16 bf16x8 __attribute__((ext_vector_type(8)));
typedef u16 u16x8 __attribute__((ext_vector_type(8)));
typedef u16 u16x4 __attribute__((ext_vector_type(4)));
typedef float f32x4 __attribute__((ext_vector_type(4)));
typedef float f32x16 __attribute__((ext_vector_type(16)));

#define BHTD 8388608  // 4*16*2048*64 elements per Q/K/V tensor
#define QSCALE 0.18033688f  // 0.125 * log2(e): softmax in exp2 domain

__device__ __forceinline__ u16 f2bf(float f) {
  union { float f; u32 u; } x; x.f = f;
  u32 r = (x.u + 0x7FFFu + ((x.u >> 16) & 1u)) >> 16;
  return (u16)r;
}

__device__ __forceinline__ u32 cvt_pk_bf16(float lo, float hi) {
  u32 r;
  asm("v_cvt_pk_bf16_f32 %0, %1, %2" : "=v"(r) : "v"(lo), "v"(hi));
  return r;
}

// v_permlane32_swap_b32: x.hi32lanes <-> y.lo32lanes (both updated in place).
__device__ __forceinline__ void permlane32_swap(u32& x, u32& y) {
  asm("v_permlane32_swap_b32 %0, %1" : "+v"(x), "+v"(y));
}

__device__ __forceinline__ void async_copy16(const u16* gsrc, u16* ldst) {
  __builtin_amdgcn_global_load_lds(
      (const __attribute__((address_space(1))) void*)gsrc,
      (__attribute__((address_space(3))) void*)ldst, 16, 0, 0);
}

// ---------------- fp32 -> bf16 elementwise convert ----------------
__global__ __launch_bounds__(256) void conv_x_kernel(const float4* __restrict__ in,
                                                     u16x4* __restrict__ out, int n4) {
  int i = blockIdx.x * 256 + threadIdx.x;
  int stride = gridDim.x * 256;
  for (; i < n4; i += stride) {
    float4 v = in[i];
    u16x4 o = { f2bf(v.x), f2bf(v.y), f2bf(v.z), f2bf(v.w) };
    out[i] = o;
  }
}

// ---------------- fp32 [K][N] -> bf16 transposed [N][K] ----------------
__global__ __launch_bounds__(256) void transpose_bf16(const float* __restrict__ W,
                                                      u16* __restrict__ Wt, int K, int N) {
  __shared__ float t[64][65];
  int c0 = blockIdx.x * 64;  // col block (N)
  int r0 = blockIdx.y * 64;  // row block (K)
  int c = threadIdx.x & 63;
  int r4 = threadIdx.x >> 6;
#pragma unroll
  for (int j = 0; j < 16; ++j) {
    int r = j * 4 + r4;
    t[r][c] = W[(size_t)(r0 + r) * N + (c0 + c)];
  }
  __syncthreads();
#pragma unroll
  for (int j = 0; j < 16; ++j) {
    int n = j * 4 + r4;
    Wt[(size_t)(c0 + n) * K + (r0 + c)] = f2bf(t[c][n]);
  }
}

// ---------------- bf16 GEMM: C[M][N] = A[M][1024] * Bt[N][1024]^T + bias ----------------
// 128x128 tile, 4 waves (2x2), BK=64, global_load_lds staging with XOR slot swizzle.
// MODE 0: scatter to QKV; Q (pre-scaled by QSCALE),K as [B][H][T][64], V TRANSPOSED
// as [B][H][64][T] (bf16).  MODE 1: fp32 out [M][1024].
template <int MODE>
__global__ __launch_bounds__(256) void gemm_bf16(const u16* __restrict__ A,
                                                 const u16* __restrict__ Bt,
                                                 const float* __restrict__ bias,
                                                 float* __restrict__ outp,
                                                 u16* __restrict__ qkv, int grid_n) {
  __shared__ __attribute__((aligned(16))) u16 A_lds[128 * 64];
  __shared__ __attribute__((aligned(16))) u16 B_lds[128 * 64];
  const int tid = threadIdx.x;
  const int lane = tid & 63, wave = tid >> 6;
  const int wr = wave >> 1, wc = wave & 1;
  const int bn = blockIdx.x % grid_n, bm = blockIdx.x / grid_n;
  const int m0 = bm * 128, n0 = bn * 128;
  const int g = lane >> 4, c16 = lane & 15;
  const int lrow = lane >> 3, lslot = lane & 7;

  f32x4 acc[4][4] = {};

  for (int kt = 0; kt < 16; ++kt) {
#pragma unroll
    for (int i = 0; i < 4; ++i) {
      int mloc = (wave * 4 + i) * 8 + lrow;
      int col = kt * 64 + ((lslot ^ (mloc & 7)) << 3);  // pre-swizzled global source
      async_copy16(&A[(size_t)(m0 + mloc) * 1024 + col], &A_lds[(wave * 4 + i) * 512]);
      async_copy16(&Bt[(size_t)(n0 + mloc) * 1024 + col], &B_lds[(wave * 4 + i) * 512]);
    }
    __syncthreads();  // compiler drains vmcnt before barrier
#pragma unroll
    for (int kk = 0; kk < 2; ++kk) {
      bf16x8 af[4], bfr[4];
#pragma unroll
      for (int mb = 0; mb < 4; ++mb) {
        int row = wr * 64 + mb * 16 + c16;
        int slot = (kk * 4 + g) ^ (row & 7);
        af[mb] = *(const bf16x8*)&A_lds[row * 64 + slot * 8];
        int rowb = wc * 64 + mb * 16 + c16;
        int slotb = (kk * 4 + g) ^ (rowb & 7);
        bfr[mb] = *(const bf16x8*)&B_lds[rowb * 64 + slotb * 8];
      }
#pragma unroll
      for (int mb = 0; mb < 4; ++mb)
#pragma unroll
        for (int nb = 0; nb < 4; ++nb)
          acc[mb][nb] = __builtin_amdgcn_mfma_f32_16x16x32_bf16(af[mb], bfr[nb], acc[mb][nb], 0, 0, 0);
    }
    __syncthreads();
  }

  float bv[4];
#pragma unroll
  for (int nb = 0; nb < 4; ++nb) bv[nb] = bias[n0 + wc * 64 + nb * 16 + c16];

#pragma unroll
  for (int mb = 0; mb < 4; ++mb) {
    int row0 = m0 + wr * 64 + mb * 16 + g * 4;
#pragma unroll
    for (int nb = 0; nb < 4; ++nb) {
      int col = n0 + wc * 64 + nb * 16 + c16;
      float bvn = bv[nb];
      if (MODE == 0) {
        int sel = col >> 10, ci = col & 1023;
        int hh = ci >> 6, d = ci & 63;
        int bb = row0 >> 11, t0 = row0 & 2047;
        float qs = (sel == 0) ? QSCALE : 1.0f;
        if (sel == 2) {
          // V transposed: [bh][d][t], 4 consecutive t -> one 8B store
          u16x4 pk;
#pragma unroll
          for (int r = 0; r < 4; ++r) pk[r] = f2bf(acc[mb][nb][r] + bvn);
          *(u16x4*)&qkv[(size_t)2 * BHTD + (((size_t)(bb * 16 + hh) * 64 + d) << 11) + t0] = pk;
        } else {
#pragma unroll
          for (int r = 0; r < 4; ++r) {
            qkv[(size_t)sel * BHTD + (((size_t)(bb * 16 + hh) * 2048 + t0 + r) << 6) + d] =
                f2bf((acc[mb][nb][r] + bvn) * qs);
          }
        }
      } else {
#pragma unroll
        for (int r = 0; r < 4; ++r)
          outp[((size_t)(row0 + r) << 10) + col] = acc[mb][nb][r] + bvn;
      }
    }
  }
}

// ---------------- causal flash attention: LDS-staged K/V, swapped-operand 32x32x16 ----------------
// 1 block = (qt, hd), 4 waves x 32 q rows. K and V tiles double-buffered in LDS
// (XOR slot-swizzle, pre-applied on the global source since global_load_lds writes
// linearly). One barrier per tile; STAGE(next) issued right after it (latency hidden
// under compute). Softmax fully in-register (swapped QK^T); P^T via cvt_pk +
// permlane32_swap. qt permuted so every CU's 4 resident blocks have equal work.
__global__ __launch_bounds__(256, 4) void attn_fwd(const u16* __restrict__ Q,
                                                   const u16* __restrict__ K,
                                                   const u16* __restrict__ VT,
                                                   u16* __restrict__ Y) {
  __shared__ __attribute__((aligned(16))) u16 Kl[2][64 * 64];
  __shared__ __attribute__((aligned(16))) u16 Vl[2][64 * 64];
  const float NEG_INF = -__builtin_inff();

  int bid = blockIdx.x;
  int j = bid >> 6, hd = bid & 63;  // hd&7 selects XCD -> 8 heads per XCD (K/V fits L2)
  // per-CU balanced qt sets: {15,0,8,7},{14,1,9,6},{13,2,10,5},{12,3,11,4} (sum 30 each)
  int qt = (j < 4) ? (15 - j) : (j < 8) ? (j - 4) : (j < 12) ? j : (19 - j);
  size_t hb = (size_t)hd * (2048 * 64);
  const u16* Qh = Q + hb;
  const u16* Kh = K + hb;
  const u16* Vh = VT + hb;  // [64][2048]
  int tid = threadIdx.x, lane = tid & 63, w = tid >> 6;
  int c32 = lane & 31, h = lane >> 5;
  int qw0 = qt * 128 + w * 32;
  int qrow = qw0 + c32;   // this lane's q row
  int qend = qw0 + 32;    // this wave's kv upper bound
  int nt = 2 * qt + 2;    // block-uniform tile count

  // staging chunk geometry: chunk c (0..511) -> LDS 16B at c*16; row=c>>3, slot=c&7;
  // global col pre-swizzled: (slot ^ (row&7))*8 elements
  int ch0 = tid, ch1 = tid + 256;
  int sr0 = ch0 >> 3, sw0 = ((ch0 & 7) ^ (sr0 & 7)) << 3;
  int sr1 = ch1 >> 3, sw1 = ((ch1 & 7) ^ (sr1 & 7)) << 3;

  bf16x8 qf[4];  // Q[qrow][dk*16 + 8h .. +7], pre-scaled by QSCALE
#pragma unroll
  for (int dk = 0; dk < 4; ++dk)
    qf[dk] = *(const bf16x8*)&Qh[(size_t)qrow * 64 + dk * 16 + 8 * h];

  float m = NEG_INF, l = 0.f;
  f32x16 o0 = {}, o1 = {};  // O^T[d][q=c32]

  // prologue: stage tile 0 into buf 0
  async_copy16(&Kh[(size_t)sr0 * 64 + sw0], &Kl[0][ch0 << 3]);
  async_copy16(&Kh[(size_t)sr1 * 64 + sw1], &Kl[0][ch1 << 3]);
  async_copy16(&Vh[(size_t)sr0 * 2048 + sw0], &Vl[0][ch0 << 3]);
  async_copy16(&Vh[(size_t)sr1 * 2048 + sw1], &Vl[0][ch1 << 3]);

  const int xs = c32 & 7;  // read-side row-xor for swizzle

  for (int it = 0; it < nt; ++it) {
    int kv0 = it << 6;
    int cb = it & 1;
    __syncthreads();  // compiler drains vmcnt first -> buf[cb] staged for all waves

    if (it + 1 < nt) {  // stage next tile into buf[cb^1]; hidden under this tile's compute
      int kv1 = kv0 + 64;
      async_copy16(&Kh[(size_t)(kv1 + sr0) * 64 + sw0], &Kl[cb ^ 1][ch0 << 3]);
      async_copy16(&Kh[(size_t)(kv1 + sr1) * 64 + sw1], &Kl[cb ^ 1][ch1 << 3]);
      async_copy16(&Vh[(size_t)sr0 * 2048 + kv1 + sw0], &Vl[cb ^ 1][ch0 << 3]);
      async_copy16(&Vh[(size_t)sr1 * 2048 + kv1 + sw1], &Vl[cb ^ 1][ch1 << 3]);
    }
    if (kv0 >= qend) continue;  // wave-uniform: done waves only stage+barrier

    // ---- kf from LDS; S^T = K * Q^T ----
    bf16x8 kf[2][4];
#pragma unroll
    for (int kb = 0; kb < 2; ++kb)
#pragma unroll
      for (int dk = 0; dk < 4; ++dk)
        kf[kb][dk] =
            *(const bf16x8*)&Kl[cb][(kb * 32 + c32) * 64 + (((2 * dk + h) ^ xs) << 3)];
    f32x16 s0 = {}, s1 = {};
    __builtin_amdgcn_s_setprio(1);
#pragma unroll
    for (int dk = 0; dk < 4; ++dk) {
      s0 = __builtin_amdgcn_mfma_f32_32x32x16_bf16(kf[0][dk], qf[dk], s0, 0, 0, 0);
      s1 = __builtin_amdgcn_mfma_f32_32x32x16_bf16(kf[1][dk], qf[dk], s1, 0, 0, 0);
    }
    __builtin_amdgcn_s_setprio(0);

    // causal mask: only tiles containing this wave's diagonal
    if (kv0 + 64 >= qend) {
      int kvb = kv0 + 4 * h;
#pragma unroll
      for (int reg = 0; reg < 16; ++reg) {
        int kvl = kvb + 8 * (reg >> 2) + (reg & 3);  // kv of s0[reg]
        if (kvl > qrow) s0[reg] = NEG_INF;
        if (kvl + 32 > qrow) s1[reg] = NEG_INF;
      }
    }

    // ---- online softmax: per-lane row, 4-chain ILP reduction + one cross-lane op ----
    float a0 = fmaxf(s0[0], s1[0]), a1 = fmaxf(s0[1], s1[1]);
    float a2 = fmaxf(s0[2], s1[2]), a3 = fmaxf(s0[3], s1[3]);
#pragma unroll
    for (int i = 4; i < 16; i += 4) {
      a0 = fmaxf(a0, fmaxf(s0[i], s1[i]));
      a1 = fmaxf(a1, fmaxf(s0[i + 1], s1[i + 1]));
      a2 = fmaxf(a2, fmaxf(s0[i + 2], s1[i + 2]));
      a3 = fmaxf(a3, fmaxf(s0[i + 3], s1[i + 3]));
    }
    float rm = fmaxf(fmaxf(a0, a1), fmaxf(a2, a3));
    rm = fmaxf(rm, __shfl_xor(rm, 32));
    if (__any(rm - m > 8.f)) {  // defer-max: rescale only when a row grew >2^8
      float mn = fmaxf(m, rm);
      float alpha = __builtin_exp2f(m - mn);
      l *= alpha;
      o0 *= alpha;
      o1 *= alpha;
      m = mn;
    }
#pragma unroll
    for (int i = 0; i < 16; ++i) s0[i] = __builtin_exp2f(s0[i] - m);
#pragma unroll
    for (int i = 0; i < 16; ++i) s1[i] = __builtin_exp2f(s1[i] - m);
    float b0 = s0[0] + s1[0], b1 = s0[1] + s1[1], b2 = s0[2] + s1[2], b3 = s0[3] + s1[3];
#pragma unroll
    for (int i = 4; i < 16; i += 4) {
      b0 += s0[i] + s1[i];
      b1 += s0[i + 1] + s1[i + 1];
      b2 += s0[i + 2] + s1[i + 2];
      b3 += s0[i + 3] + s1[i + 3];
    }
    float rs = (b0 + b1) + (b2 + b3);
    rs += __shfl_xor(rs, 32);
    l += rs;

    // ---- P^T: pack pairs to bf16, half-exchange via permlane32_swap ----
    u32 pw0[8], pw1[8];
#pragma unroll
    for (int mm = 0; mm < 8; ++mm) {
      pw0[mm] = cvt_pk_bf16(s0[2 * mm], s0[2 * mm + 1]);
      pw1[mm] = cvt_pk_bf16(s1[2 * mm], s1[2 * mm + 1]);
    }
    permlane32_swap(pw0[0], pw0[2]); permlane32_swap(pw0[1], pw0[3]);
    permlane32_swap(pw0[4], pw0[6]); permlane32_swap(pw0[5], pw0[7]);
    permlane32_swap(pw1[0], pw1[2]); permlane32_swap(pw1[1], pw1[3]);
    permlane32_swap(pw1[4], pw1[6]); permlane32_swap(pw1[5], pw1[7]);

    // ---- O^T += V^T * P^T, V fragments from LDS ----
    __builtin_amdgcn_s_setprio(1);
#pragma unroll
    for (int c = 0; c < 4; ++c) {
      const u32* pp = (c >> 1) ? pw1 : pw0;
      const int a = 4 * (c & 1);
      union { u32 u[4]; bf16x8 v; } pf;
      pf.u[0] = pp[a + 0];
      pf.u[1] = pp[a + 1];
      pf.u[2] = pp[a + 2];
      pf.u[3] = pp[a + 3];
      bf16x8 vf0 = *(const bf16x8*)&Vl[cb][c32 * 64 + (((2 * c + h) ^ xs) << 3)];
      bf16x8 vf1 = *(const bf16x8*)&Vl[cb][(32 + c32) * 64 + (((2 * c + h) ^ xs) << 3)];
      o0 = __builtin_amdgcn_mfma_f32_32x32x16_bf16(vf0, pf.v, o0, 0, 0, 0);
      o1 = __builtin_amdgcn_mfma_f32_32x32x16_bf16(vf1, pf.v, o1, 0, 0, 0);
    }
    __builtin_amdgcn_s_setprio(0);
  }

  // epilogue: lane owns row q=qrow; O^T reg (db,rq,j) -> d = db*32 + 8*rq + 4*h + j
  float inv = 1.0f / l;
  size_t yb = (size_t)(hd >> 4) * (2048 * 1024) + (size_t)(hd & 15) * 64 + (size_t)qrow * 1024;
#pragma unroll
  for (int db = 0; db < 2; ++db)
#pragma unroll
    for (int rq = 0; rq < 4; ++rq) {
      u16x4 pk;
#pragma unroll
      for (int jj = 0; jj < 4; ++jj)
        pk[jj] = f2bf((db ? o1[rq * 4 + jj] : o0[rq * 4 + jj]) * inv);
      *(u16x4*)&Y[yb + db * 32 + 8 * rq + 4 * h] = pk;
    }
}

extern "C" void kernel_launch(void* const* d_in, const int* in_sizes, int n_in,
                              void* d_out, int out_size, void* d_ws, size_t ws_size,
                              hipStream_t stream) {
  (void)in_sizes; (void)n_in; (void)out_size; (void)ws_size;
  const float* x      = (const float*)d_in[0];
  const float* W_attn = (const float*)d_in[1];
  const float* b_attn = (const float*)d_in[2];
  const float* W_proj = (const float*)d_in[3];
  const float* b_proj = (const float*)d_in[4];
  float* out = (float*)d_out;

  char* ws = (char*)d_ws;
  u16* Xb  = (u16*)(ws);                                   // 8192*1024 bf16 (reused as Yb)
  u16* Wt  = (u16*)(ws + 16777216);                        // 3072*1024 bf16
  u16* Wpt = (u16*)(ws + 16777216 + 6291456);              // 1024*1024 bf16
  u16* QKV = (u16*)(ws + 16777216 + 6291456 + 2097152);    // 3 * 8388608 bf16
  u16* Yb  = Xb;

  conv_x_kernel<<<2048, 256, 0, stream>>>((const float4*)x, (u16x4*)Xb, 2097152);
  transpose_bf16<<<dim3(48, 16), 256, 0, stream>>>(W_attn, Wt, 1024, 3072);
  transpose_bf16<<<dim3(16, 16), 256, 0, stream>>>(W_proj, Wpt, 1024, 1024);
  gemm_bf16<0><<<1536, 256, 0, stream>>>(Xb, Wt, b_attn, nullptr, QKV, 24);
  attn_fwd<<<1024, 256, 0, stream>>>(QKV, QKV + BHTD, QKV + 2 * BHTD, Yb);
  gemm_bf16<1><<<512, 256, 0, stream>>>(Yb, Wpt, b_proj, out, nullptr, 8);
}